// Round 1
// baseline (14031.396 us; speedup 1.0000x reference)
//
#include <hip/hip_runtime.h>
#include <math.h>

// Ring-attractor recurrence, persistent-kernel design.
// 64 blocks; block bi owns output neurons i in [bi*4, bi*4+4) for ALL batches.
// Per block LDS: 36 weight rows (W_base + 8 Wa) for its 4 neurons, full r state.
// Per step: 36x64 dots from LDS -> combine with A(t) -> tanh-leak update ->
// write r chunk to r_hist -> device barrier (bar[t] counter in ws) ->
// reload full r from r_hist -> rank-2 W_delta7 projection (c,s vectors) -> bump out.

#define NBLK  64
#define NTHR  256
#define BATCH 64
#define TT    512
#define NN    256
#define ADIM  8
#define IC    4      // neurons per block
#define ROWS  36     // 9 * IC  (mat 0 = W_base, 1..8 = Wa[a])
#define WPAD  260    // pad: bank base steps by 4 per row -> <=2-way conflicts
#define RPAD  260
#define MPAD  66

__global__ __launch_bounds__(NTHR, 1)
void ring_attractor_kernel(const float* __restrict__ act,     // [64,512,8]
                           const float* __restrict__ r_init,  // [64,256]
                           const float* __restrict__ Wo,      // [256,256]
                           const float* __restrict__ Wa,      // [8,256,256]
                           const float* __restrict__ J0,      // [256,256]
                           const float* __restrict__ Wd7,     // [256,256]
                           float* __restrict__ out,           // r_hist | bump
                           unsigned int* __restrict__ bar)    // [512] zeroed
{
  __shared__ float Wl[ROWS][WPAD];   // weight rows for this block's neurons
  __shared__ float Rl[BATCH][RPAD];  // full current state r[b][j]
  __shared__ float mql[ROWS][MPAD];  // per-matrix dot results m[row][b]
  __shared__ float cvec[NN];         // cos(theta_j) = Wd7[j][0]
  __shared__ float svec[NN];         // sin(theta_j) = Wd7[j][64]
  __shared__ float Atl[BATCH][9];    // A(t), padded
  __shared__ float CSl[BATCH][2];    // C,S projections
  __shared__ float sums[3];          // sum c^2, sum c*s, sum s^2

  const int tid = threadIdx.x;
  const int bi  = blockIdx.x;
  const int i0  = bi * IC;

  float* out_r = out;
  float* out_b = out + (size_t)BATCH * TT * NN;

  // ---------------- init (once) ----------------
  for (int idx = tid; idx < NN; idx += NTHR) {
    cvec[idx] = Wd7[idx * NN];        // cos(2*pi*i/N), exact buffer values
    svec[idx] = Wd7[idx * NN + 64];   // cos(2*pi*(i-64)/N) = sin(2*pi*i/N)
  }
  for (int idx = tid; idx < ROWS * NN; idx += NTHR) {
    const int row = idx >> 8;
    const int j   = idx & 255;
    const int il  = row / 9;
    const int mat = row % 9;
    const int gi  = i0 + il;
    float w;
    if (mat == 0) w = J0[gi * NN + j] + 0.1f * Wo[gi * NN + j];   // J0 + J1*Wo
    else          w = Wa[((mat - 1) * NN + gi) * NN + j];
    Wl[row][j] = w;
  }
  for (int idx = tid; idx < BATCH * NN; idx += NTHR)
    Rl[idx >> 8][idx & 255] = r_init[idx];
  __syncthreads();
  if (tid == 0) {
    float scc = 0.f, scs = 0.f, sss = 0.f;
    for (int j = 0; j < NN; ++j) {
      const float c = cvec[j], s = svec[j];
      scc += c * c; scs += c * s; sss += s * s;
    }
    sums[0] = scc; sums[1] = scs; sums[2] = sss;
  }
  __syncthreads();

  // ---------------- time loop ----------------
  for (int t = 0; t < TT; ++t) {
    // load A(t) for all batches
    for (int idx = tid; idx < BATCH * ADIM; idx += NTHR)
      Atl[idx >> 3][idx & 7] = act[((size_t)(idx >> 3) * TT + t) * ADIM + (idx & 7)];
    __syncthreads();

    // dot phase: 144 threads, each 4 rows x 4 batches (strided tiles so
    // lane address strides hit distinct banks; WPAD/RPAD=260 -> <=2-way)
    if (tid < 144) {
      const int rt = tid >> 4;   // 0..8  -> rows rt, rt+9, rt+18, rt+27
      const int bt = tid & 15;   // 0..15 -> batches bt, bt+16, bt+32, bt+48
      float acc[4][4] = {};
      #pragma unroll 2
      for (int j = 0; j < NN; j += 4) {
        float4 w[4], x[4];
        #pragma unroll
        for (int k = 0; k < 4; ++k) w[k] = *(const float4*)&Wl[rt + 9 * k][j];
        #pragma unroll
        for (int k = 0; k < 4; ++k) x[k] = *(const float4*)&Rl[bt + 16 * k][j];
        #pragma unroll
        for (int ri = 0; ri < 4; ++ri)
          #pragma unroll
          for (int ci = 0; ci < 4; ++ci)
            acc[ri][ci] += w[ri].x * x[ci].x + w[ri].y * x[ci].y
                         + w[ri].z * x[ci].z + w[ri].w * x[ci].w;
      }
      #pragma unroll
      for (int ri = 0; ri < 4; ++ri)
        #pragma unroll
        for (int ci = 0; ci < 4; ++ci)
          mql[rt + 9 * ri][bt + 16 * ci] = acc[ri][ci];
    }
    __syncthreads();

    // combine + tanh-leak update + publish r chunk to r_hist
    {
      const int b  = tid >> 2;
      const int il = tid & 3;
      float rec = mql[il * 9][b];
      #pragma unroll
      for (int a = 0; a < ADIM; ++a)
        rec += Atl[b][a] * mql[il * 9 + 1 + a][b];
      const int gi = i0 + il;
      const float rold = Rl[b][gi];
      const float rnew = rold + 0.1f * (tanhf(rec) - rold);  // DT/TAU = 0.1
      out_r[((size_t)b * TT + t) * NN + gi] = rnew;
    }

    // ---- device-scope step barrier (counter bar[t], used exactly once) ----
    __threadfence();
    __syncthreads();
    if (tid == 0) {
      __hip_atomic_fetch_add(&bar[t], 1u, __ATOMIC_ACQ_REL, __HIP_MEMORY_SCOPE_AGENT);
      while (__hip_atomic_load(&bar[t], __ATOMIC_ACQUIRE, __HIP_MEMORY_SCOPE_AGENT)
             < (unsigned)NBLK)
        __builtin_amdgcn_s_sleep(1);
    }
    __syncthreads();
    __threadfence();

    // reload full r(t) from r_hist[:, t, :]
    {
      const float* rsrc = out_r + (size_t)t * NN;
      for (int q = tid; q < BATCH * (NN / 4); q += NTHR) {
        const int b  = q >> 6;
        const int j4 = q & 63;
        const float4 v = *(const float4*)(rsrc + (size_t)b * TT * NN + j4 * 4);
        *(float4*)&Rl[b][j4 * 4] = v;
      }
    }
    __syncthreads();

    // C,S projections: 4 threads per batch, 64 j each, quad shuffle-reduce
    {
      const int b   = tid >> 2;
      const int seg = tid & 3;
      float C = 0.f, S = 0.f;
      const int j0 = seg * 64;
      #pragma unroll 4
      for (int j = j0; j < j0 + 64; ++j) {
        const float rv = Rl[b][j];
        C += cvec[j] * rv;
        S += svec[j] * rv;
      }
      C += __shfl_xor(C, 1); C += __shfl_xor(C, 2);
      S += __shfl_xor(S, 1); S += __shfl_xor(S, 2);
      if (seg == 0) { CSl[b][0] = C; CSl[b][1] = S; }
    }
    __syncthreads();

    // bump output: d7 = c_i*C + s_i*S, ||d7||^2 = scc*C^2 + 2*scs*C*S + sss*S^2
    {
      const int b  = tid >> 2;
      const int il = tid & 3;
      const float C = CSl[b][0], S = CSl[b][1];
      const float n2  = sums[0] * C * C + 2.f * sums[1] * C * S + sums[2] * S * S;
      const float inv = 1.0f / sqrtf(n2);
      const int gi = i0 + il;
      out_b[((size_t)b * TT + t) * NN + gi] = (cvec[gi] * C + svec[gi] * S) * inv;
    }
    __syncthreads();
  }
}

extern "C" void kernel_launch(void* const* d_in, const int* in_sizes, int n_in,
                              void* d_out, int out_size, void* d_ws, size_t ws_size,
                              hipStream_t stream) {
  const float* act    = (const float*)d_in[0];
  const float* r_init = (const float*)d_in[1];
  const float* Wo     = (const float*)d_in[2];
  const float* Wa     = (const float*)d_in[3];
  const float* J0     = (const float*)d_in[4];
  const float* Wd7    = (const float*)d_in[5];
  float* out = (float*)d_out;
  unsigned int* bar = (unsigned int*)d_ws;

  // zero the 512 per-step barrier counters (ws is re-poisoned each launch)
  hipMemsetAsync(d_ws, 0, TT * sizeof(unsigned int), stream);

  hipLaunchKernelGGL(ring_attractor_kernel, dim3(NBLK), dim3(NTHR), 0, stream,
                     act, r_init, Wo, Wa, J0, Wd7, out, bar);
}